// Round 3
// baseline (281438.696 us; speedup 1.0000x reference)
//
#include <hip/hip_runtime.h>
#include <hip/hip_cooperative_groups.h>

#define SEQ  8192
#define NT   2048
#define NBLK 256
#define NTHR 512
#define LOG2E 1.4426950408889634f
#define LN2   0.6931471805599453f

#define LOAD_AG(p)     __hip_atomic_load((p), __ATOMIC_RELAXED, __HIP_MEMORY_SCOPE_AGENT)
#define STORE_AG(p, v) __hip_atomic_store((p), (v), __ATOMIC_RELAXED, __HIP_MEMORY_SCOPE_AGENT)
#define FENCE_ACQ()    __builtin_amdgcn_fence(__ATOMIC_ACQUIRE, "agent")
#define FENCE_REL()    __builtin_amdgcn_fence(__ATOMIC_RELEASE, "agent")

// Double-buffered forward variables (log2 domain), per-block step flags, gold.
// Device globals; re-initialized by crf_init on every call (graph replay safe).
__device__ float g_fv[2][NT];
__device__ int   g_flag[NBLK];
__device__ float g_gold;

// ---- init: fv0 = (T_start + feats[0]) * log2(e); zero flags ----
__global__ void crf_init(const float* __restrict__ feats,
                         const float* __restrict__ tstart) {
    int i = blockIdx.x * blockDim.x + threadIdx.x;
    if (i < NT)   g_fv[0][i] = (tstart[i] + feats[i]) * LOG2E;
    if (i < NBLK) g_flag[i] = 0;
}

// ---- gold path score (natural log domain) ----
__global__ void crf_gold(const float* __restrict__ feats,
                         const float* __restrict__ trans,
                         const float* __restrict__ tstart,
                         const float* __restrict__ tstop,
                         const int*   __restrict__ tags) {
    __shared__ float part[16];
    int tid = threadIdx.x;
    float acc = 0.f;
    for (int t = 1 + tid; t < SEQ; t += 1024) {
        int cur = tags[t], prev = tags[t - 1];
        acc += trans[(size_t)cur * NT + prev] + feats[(size_t)t * NT + cur];
    }
    #pragma unroll
    for (int m = 1; m < 64; m <<= 1) acc += __shfl_xor(acc, m, 64);
    if ((tid & 63) == 0) part[tid >> 6] = acc;
    __syncthreads();
    if (tid == 0) {
        float S = 0.f;
        #pragma unroll
        for (int w = 0; w < 16; ++w) S += part[w];
        int t0 = tags[0], tl = tags[SEQ - 1];
        g_gold = S + tstart[t0] + feats[t0] + tstop[tl];
    }
}

// ---- main recurrence ----
// 256 blocks x 512 threads (8 waves). Wave r of block b owns output row
// j = 8b + r, with E[j, l + 64k] (k<32) held in 32 VGPRs per lane.
// Per step: hand-rolled flag barrier -> w = exp2(fv - s) into LDS ->
// 32 reg-FMAs vs LDS -> shfl reduce -> log2 -> publish fv + flag.
__global__ void __launch_bounds__(NTHR)
crf_main(const float* __restrict__ feats, const float* __restrict__ trans,
         const float* __restrict__ tstop, float* __restrict__ out) {
    const int b   = blockIdx.x;
    const int tid = threadIdx.x;
    const int wv  = tid >> 6;
    const int l   = tid & 63;
    const int j   = b * 8 + wv;

    __shared__ float w_lds[NT];
    __shared__ float red[8];

    // One-time: E row into registers. E = exp2(T * log2e) = exp(T) in [1, e).
    float E[32];
    {
        const float* trow = trans + (size_t)j * NT;
        #pragma unroll
        for (int k = 0; k < 32; ++k)
            E[k] = __builtin_exp2f(trow[l + (k << 6)] * LOG2E);
    }

    float featv = feats[(size_t)1 * NT + j];  // feat for step 1 (lane0's copy used)

    int par = 0;
    for (int t = 1; t < SEQ; ++t) {
        // ---- barrier: wait for every block to have published step t-1 ----
        if (tid < NBLK) {
            while (LOAD_AG(&g_flag[tid]) < t - 1) { }
        }
        __syncthreads();
        FENCE_ACQ();

        float* fvin  = g_fv[par];
        float* fvout = g_fv[par ^ 1];

        // ---- w = exp2(fv - s) into LDS (block-cooperative, coalesced) ----
        float s = LOAD_AG(&fvin[0]);  // global shift; w[0] == 1 guarantees sum >= 1
        #pragma unroll
        for (int q = 0; q < 4; ++q) {
            int i = tid + q * NTHR;
            float v = LOAD_AG(&fvin[i]);
            w_lds[i] = __builtin_exp2f(v - s);
        }
        // prefetch next step's feat (uniform addr per wave -> single fetch)
        float featnext = (t + 1 < SEQ) ? feats[(size_t)(t + 1) * NT + j] : 0.f;
        __syncthreads();

        // ---- dot: acc = sum_k E[j, l+64k] * w[l+64k]  (2-way LDS alias = free) ----
        float acc = 0.f;
        #pragma unroll
        for (int k = 0; k < 32; ++k)
            acc = fmaf(E[k], w_lds[l + (k << 6)], acc);
        #pragma unroll
        for (int m = 1; m < 64; m <<= 1) acc += __shfl_xor(acc, m, 64);

        if (l == 0) {
            float nf = s + __builtin_log2f(acc) + featv * LOG2E;
            STORE_AG(&fvout[j], nf);
        }
        featv = featnext;

        // publish: release fence drains fv stores to LLC, then one flag store
        // after the block barrier.
        FENCE_REL();
        __syncthreads();
        if (tid == 0) STORE_AG(&g_flag[b], t);

        par ^= 1;
    }

    // ---- final logsumexp with stop transitions, minus gold ----
    if (b == 0) {
        if (tid < NBLK) {
            while (LOAD_AG(&g_flag[tid]) < SEQ - 1) { }
        }
        __syncthreads();
        FENCE_ACQ();

        float* fv = g_fv[(SEQ - 1) & 1];
        float s = LOAD_AG(&fv[0]);
        float acc = 0.f;
        #pragma unroll
        for (int q = 0; q < 4; ++q) {
            int i = tid + q * NTHR;
            float v = LOAD_AG(&fv[i]);
            acc += __builtin_exp2f(v - s + tstop[i] * LOG2E);
        }
        #pragma unroll
        for (int m = 1; m < 64; m <<= 1) acc += __shfl_xor(acc, m, 64);
        if (l == 0) red[wv] = acc;
        __syncthreads();
        if (tid == 0) {
            float S = 0.f;
            #pragma unroll
            for (int w = 0; w < 8; ++w) S += red[w];
            float fwd = (s + __builtin_log2f(S)) * LN2;
            out[0] = fwd - g_gold;
        }
    }
}

extern "C" void kernel_launch(void* const* d_in, const int* in_sizes, int n_in,
                              void* d_out, int out_size, void* d_ws, size_t ws_size,
                              hipStream_t stream) {
    const float* feats  = (const float*)d_in[0];
    const float* trans  = (const float*)d_in[1];
    const float* tstart = (const float*)d_in[2];
    const float* tstop  = (const float*)d_in[3];
    const int*   tags   = (const int*)d_in[4];
    float* out = (float*)d_out;

    hipLaunchKernelGGL(crf_init, dim3(2), dim3(1024), 0, stream, feats, tstart);
    hipLaunchKernelGGL(crf_gold, dim3(1), dim3(1024), 0, stream,
                       feats, trans, tstart, tstop, tags);

    void* args[] = { (void*)&feats, (void*)&trans, (void*)&tstop, (void*)&out };
    hipLaunchCooperativeKernel((void*)crf_main, dim3(NBLK), dim3(NTHR),
                               args, 0, stream);
}

// Round 4
// 22296.193 us; speedup vs baseline: 12.6227x; 12.6227x over previous
//
#include <hip/hip_runtime.h>

#define SEQ  8192
#define NT   2048
#define NBLK 256
#define NTHR 512
#define LOG2E 1.4426950408889634f
#define LN2   0.6931471805599453f

#define LOAD_AG(p)     __hip_atomic_load((p), __ATOMIC_RELAXED, __HIP_MEMORY_SCOPE_AGENT)
#define STORE_AG(p, v) __hip_atomic_store((p), (v), __ATOMIC_RELAXED, __HIP_MEMORY_SCOPE_AGENT)

// Packed state: hi16 = step tag, lo16 = bf16(z) bits. Double-buffered by t&1.
// Tag+data in ONE word => a single relaxed store publishes both atomically:
// no flags, no fences, no barrier. Device globals re-init'd every call.
__device__ unsigned int g_z[2][NT];
__device__ float g_gold;

__device__ __forceinline__ unsigned int f32_to_bf16(float f) {
    unsigned int u = __float_as_uint(f);
    return (u + 0x7FFFu + ((u >> 16) & 1u)) >> 16;  // RNE
}

// ---- init: z0 = exp(tstart + feats[0]) packed with tag 0; buf1 invalidated ----
__global__ void crf_init(const float* __restrict__ feats,
                         const float* __restrict__ tstart) {
    int i = blockIdx.x * blockDim.x + threadIdx.x;
    if (i < NT) {
        float z0 = __builtin_exp2f((tstart[i] + feats[i]) * LOG2E);
        g_z[0][i] = f32_to_bf16(z0);   // tag 0 in hi16
        g_z[1][i] = 0xFFFF0000u;       // tag 0xFFFF: never matches (t <= 8191)
    }
}

// ---- gold path score (unchanged; verified) ----
__global__ void crf_gold(const float* __restrict__ feats,
                         const float* __restrict__ trans,
                         const float* __restrict__ tstart,
                         const float* __restrict__ tstop,
                         const int*   __restrict__ tags) {
    __shared__ float part[16];
    int tid = threadIdx.x;
    float acc = 0.f;
    for (int t = 1 + tid; t < SEQ; t += 1024) {
        int cur = tags[t], prev = tags[t - 1];
        acc += trans[(size_t)cur * NT + prev] + feats[(size_t)t * NT + cur];
    }
    #pragma unroll
    for (int m = 1; m < 64; m <<= 1) acc += __shfl_xor(acc, m, 64);
    if ((tid & 63) == 0) part[tid >> 6] = acc;
    __syncthreads();
    if (tid == 0) {
        float S = 0.f;
        #pragma unroll
        for (int w = 0; w < 16; ++w) S += part[w];
        int t0 = tags[0], tl = tags[SEQ - 1];
        g_gold = S + tstart[t0] + feats[t0] + tstop[tl];
    }
}

// ---- main recurrence: 256 blocks x 512 threads, wave wv owns row j=8b+wv ----
// Linear domain: z_t = (E z_{t-1}) * exp(feat_t) * 2^-e, e = exponent(z[0])
// (exact shift, same in every block; integer-accumulated for the final log).
// Lockstep emerges from the data dependency itself: a block can only write
// z_t after reading ALL of z_{t-1}, so when anyone is at step t, everyone
// has finished t-1 => double-buffer slots being overwritten (z_{t-2}) are
// dead and tags are never missed. One __syncthreads per step, nothing else.
__global__ void __launch_bounds__(NTHR)
crf_main(const float* __restrict__ feats, const float* __restrict__ trans,
         const float* __restrict__ tstop, float* __restrict__ out) {
    const int b   = blockIdx.x;
    const int tid = threadIdx.x;
    const int wv  = tid >> 6;
    const int l   = tid & 63;
    const int j   = b * 8 + wv;

    __shared__ float w_lds[2][NT];   // parity double-buffer (no tail barrier)
    __shared__ float s_scale[2];
    __shared__ float red[8];

    // E row in registers: E[j, l+64k] = exp(T[j, l+64k]) in [1, e)
    float E[32];
    {
        const float* trow = trans + (size_t)j * NT;
        #pragma unroll
        for (int k = 0; k < 32; ++k)
            E[k] = __builtin_exp2f(trow[l + (k << 6)] * LOG2E);
    }

    float featv = feats[(size_t)NT + j];  // feat for step 1
    int esum = 0;                         // only block 0 / tid 0's value is used

    for (int t = 1; t < SEQ; ++t) {
        const int par = (t - 1) & 1;
        const unsigned int need = (unsigned int)(t - 1);
        unsigned int* buf = g_z[par];

        // poll own 4 slots (coalesced, LLC); unpack bf16 -> f32 into LDS
        #pragma unroll
        for (int q = 0; q < 4; ++q) {
            int i = tid + q * NTHR;
            unsigned int v;
            do { v = LOAD_AG(&buf[i]); } while ((v >> 16) != need);
            w_lds[par][i] = __uint_as_float(v << 16);
        }
        if (tid == 0) {
            unsigned int bits = __float_as_uint(w_lds[par][0]);
            int e = (int)((bits >> 23) & 0xFFu) - 127;
            s_scale[par] = __uint_as_float((unsigned int)(127 - e) << 23);
            esum += e;
        }
        // prefetch next feat (wave-uniform address)
        float featnext = (t + 1 < SEQ) ? feats[(size_t)(t + 1) * NT + j] : 0.f;
        __syncthreads();

        // dot: acc = sum_k E[j, l+64k] * w[l+64k]  (2-way LDS alias = free)
        float acc = 0.f;
        #pragma unroll
        for (int k = 0; k < 32; ++k)
            acc = fmaf(E[k], w_lds[par][l + (k << 6)], acc);
        #pragma unroll
        for (int m = 1; m < 64; m <<= 1) acc += __shfl_xor(acc, m, 64);

        if (l == 0) {
            float znew = acc * s_scale[par] * __builtin_exp2f(featv * LOG2E);
            STORE_AG(&g_z[t & 1][j],
                     ((unsigned int)t << 16) | f32_to_bf16(znew));
        }
        featv = featnext;
        // no bottom barrier: w_lds/s_scale parity + lockstep proof cover reuse
    }

    // ---- final: lse of z_{SEQ-1} with stop transitions, minus gold ----
    if (b == 0) {
        const unsigned int need = SEQ - 1;
        unsigned int* buf = g_z[(SEQ - 1) & 1];
        float acc = 0.f;
        #pragma unroll
        for (int q = 0; q < 4; ++q) {
            int i = tid + q * NTHR;
            unsigned int v;
            do { v = LOAD_AG(&buf[i]); } while ((v >> 16) != need);
            float w = __uint_as_float(v << 16);
            acc += w * __builtin_exp2f(tstop[i] * LOG2E);
        }
        #pragma unroll
        for (int m = 1; m < 64; m <<= 1) acc += __shfl_xor(acc, m, 64);
        if (l == 0) red[wv] = acc;
        __syncthreads();
        if (tid == 0) {
            float S = 0.f;
            #pragma unroll
            for (int w = 0; w < 8; ++w) S += red[w];
            float fwd = (__builtin_log2f(S) + (float)esum) * LN2;
            out[0] = fwd - g_gold;
        }
    }
}

extern "C" void kernel_launch(void* const* d_in, const int* in_sizes, int n_in,
                              void* d_out, int out_size, void* d_ws, size_t ws_size,
                              hipStream_t stream) {
    const float* feats  = (const float*)d_in[0];
    const float* trans  = (const float*)d_in[1];
    const float* tstart = (const float*)d_in[2];
    const float* tstop  = (const float*)d_in[3];
    const int*   tags   = (const int*)d_in[4];
    float* out = (float*)d_out;

    hipLaunchKernelGGL(crf_init, dim3(2), dim3(1024), 0, stream, feats, tstart);
    hipLaunchKernelGGL(crf_gold, dim3(1), dim3(1024), 0, stream,
                       feats, trans, tstart, tstop, tags);
    hipLaunchKernelGGL(crf_main, dim3(NBLK), dim3(NTHR), 0, stream,
                       feats, trans, tstop, out);
}